// Round 1
// baseline (256.433 us; speedup 1.0000x reference)
//
#include <hip/hip_runtime.h>

typedef _Float16 v8h __attribute__((ext_vector_type(8)));
typedef float v4f __attribute__((ext_vector_type(4)));
#define HF _Float16

// dims
#define Bn 8
#define Cc 512
#define CI 256
#define HW 4096   // 64*64
#define Mp 1024   // 32*32 pooled

// ---------------- prep: weights fp32->f16, BN fold ----------------
__global__ __launch_bounds__(256) void prep_kernel(
    const float* __restrict__ w_g, const float* __restrict__ b_g,
    const float* __restrict__ w_th, const float* __restrict__ b_th,
    const float* __restrict__ w_ph, const float* __restrict__ b_ph,
    const float* __restrict__ w_out, const float* __restrict__ b_out,
    const float* __restrict__ gamma, const float* __restrict__ beta,
    const float* __restrict__ mean, const float* __restrict__ var,
    HF* __restrict__ wall, float* __restrict__ ball,
    HF* __restrict__ wo, float* __restrict__ scale, float* __restrict__ shift)
{
    int idx = blockIdx.x * 256 + threadIdx.x;
    if (idx < 768*512) {
        int o = idx >> 9;
        float v = (o < 256) ? w_th[idx] : (o < 512) ? w_ph[idx - 256*512] : w_g[idx - 512*512];
        wall[idx] = (HF)v;
    }
    if (idx < 512*256) wo[idx] = (HF)w_out[idx];
    if (idx < 768) ball[idx] = (idx < 256) ? b_th[idx] : (idx < 512) ? b_ph[idx-256] : b_g[idx-512];
    if (idx < 512) {
        float inv = gamma[idx] * rsqrtf(var[idx] + 1e-5f);
        scale[idx] = inv;
        shift[idx] = (b_out[idx] - mean[idx]) * inv + beta[idx];
    }
}

// ---------------- transpose x: (b,c,s) fp32 -> xT (b,s,c) f16 ----------------
__global__ __launch_bounds__(256) void transpose_x_kernel(const float* __restrict__ x, HF* __restrict__ xT)
{
    __shared__ float tile[64][65];
    int b = blockIdx.z;
    int c0 = blockIdx.y * 64, s0 = blockIdx.x * 64;
    int tr = threadIdx.x >> 6, ts = threadIdx.x & 63;
    #pragma unroll
    for (int i = 0; i < 16; ++i) {
        int r = tr + i*4;
        tile[r][ts] = x[((long)(b*Cc) + c0 + r)*HW + s0 + ts];
    }
    __syncthreads();
    #pragma unroll
    for (int i = 0; i < 16; ++i) {
        int r = tr + i*4;
        xT[((long)b*HW + s0 + r)*Cc + c0 + ts] = (HF)tile[ts][r];
    }
}

// ---------------- generic f16 transpose per batch: src[R][Cn] -> dst[Cn][R] ----------------
__global__ __launch_bounds__(256) void transpose_h_kernel(const HF* __restrict__ src, long sSrc,
                                                          HF* __restrict__ dst, long sDst,
                                                          int R, int Cn)
{
    __shared__ HF tile[64][65];
    int b = blockIdx.z;
    int r0 = blockIdx.y * 64, c0 = blockIdx.x * 64;
    const HF* S = src + (long)b * sSrc;
    HF* D = dst + (long)b * sDst;
    int tr = threadIdx.x >> 6, tc = threadIdx.x & 63;
    #pragma unroll
    for (int i = 0; i < 16; ++i) {
        int r = tr + i*4;
        tile[r][tc] = S[(long)(r0 + r)*Cn + c0 + tc];
    }
    __syncthreads();
    #pragma unroll
    for (int i = 0; i < 16; ++i) {
        int r = tr + i*4;
        D[(long)(c0 + r)*R + r0 + tc] = tile[tc][r];
    }
}

// ---------------- 2x2 maxpool: src (b,c,64,64) -> dst (b,c,32,32), c-major kept ----------------
__global__ __launch_bounds__(256) void pool_kernel(const HF* __restrict__ src, long sSrc,
                                                   HF* __restrict__ dst, long sDst)
{
    long idx = (long)blockIdx.x * 256 + threadIdx.x;   // Bn*256*1024
    int m = idx & 1023;
    long bc = idx >> 10;
    int c = (int)(bc & 255);
    int b = (int)(bc >> 8);
    int h2 = m >> 5, w2 = m & 31;
    const HF* p = src + (long)b*sSrc + (long)c*HW + h2*128 + w2*2;
    float v = fmaxf(fmaxf((float)p[0], (float)p[1]), fmaxf((float)p[64], (float)p[65]));
    dst[(long)b*sDst + (long)c*Mp + m] = (HF)v;
}

// ---------------- generic tiled gemm_bt: C[i,j] = sum_k A[i,k]*B[j,k] ----------------
// A: M x K (K contig), B: N x K (K contig). 128x128 tile, BK=32, 4 waves (2x2), f16 MFMA.
// EPI 0: C f16 = acc + rowBias[i]       (projection)
// EPI 1: C f16 = acc                    (y = attn @ g^T)
// EPI 2: C f32 = acc*scale[i] + shift[i] + Xres  (final conv + BN + residual)
template<int EPI>
__global__ __launch_bounds__(256) void gemm_bt_kernel(
    const HF* __restrict__ A, long sA, const HF* __restrict__ B, long sB,
    void* __restrict__ Cv, long sC, int M, int N, int K,
    const float* __restrict__ rowBias,
    const float* __restrict__ rowScale, const float* __restrict__ rowShift,
    const float* __restrict__ Xres, long sX)
{
    __shared__ HF As[128][40];
    __shared__ HF Bs[128][40];
    int b = blockIdx.z;
    int i0 = blockIdx.y * 128;
    int j0 = blockIdx.x * 128;
    const HF* Ab = A + (long)b * sA;
    const HF* Bb = B + (long)b * sB;
    int tid = threadIdx.x;
    int lane = tid & 63, w = tid >> 6;
    int wr = w >> 1, wc = w & 1;
    int lr = lane & 15, lk = (lane >> 4) * 8;

    v4f acc[4][4];
    #pragma unroll
    for (int i = 0; i < 4; ++i)
        #pragma unroll
        for (int j = 0; j < 4; ++j) { v4f z = {0.f,0.f,0.f,0.f}; acc[i][j] = z; }

    for (int k0 = 0; k0 < K; k0 += 32) {
        #pragma unroll
        for (int q = 0; q < 2; ++q) {
            int ch = tid*2 + q;          // 0..511
            int row = ch >> 2;
            int c8 = (ch & 3) * 8;
            const uint4* ga = (const uint4*)(Ab + (long)(i0+row)*K + k0 + c8);
            *(uint4*)(&As[row][c8]) = *ga;
            const uint4* gb = (const uint4*)(Bb + (long)(j0+row)*K + k0 + c8);
            *(uint4*)(&Bs[row][c8]) = *gb;
        }
        __syncthreads();
        v8h af[4], bfr[4];
        #pragma unroll
        for (int mf = 0; mf < 4; ++mf)
            af[mf] = *(const v8h*)(&As[wr*64 + mf*16 + lr][lk]);
        #pragma unroll
        for (int nf = 0; nf < 4; ++nf)
            bfr[nf] = *(const v8h*)(&Bs[wc*64 + nf*16 + lr][lk]);
        #pragma unroll
        for (int mf = 0; mf < 4; ++mf)
            #pragma unroll
            for (int nf = 0; nf < 4; ++nf)
                acc[mf][nf] = __builtin_amdgcn_mfma_f32_16x16x32_f16(af[mf], bfr[nf], acc[mf][nf], 0, 0, 0);
        __syncthreads();
    }

    int rbase = (lane >> 4) * 4;
    #pragma unroll
    for (int mf = 0; mf < 4; ++mf) {
        #pragma unroll
        for (int nf = 0; nf < 4; ++nf) {
            #pragma unroll
            for (int r = 0; r < 4; ++r) {
                int row = i0 + wr*64 + mf*16 + rbase + r;
                int col = j0 + wc*64 + nf*16 + lr;
                float v = acc[mf][nf][r];
                if (EPI == 0) {
                    v += rowBias[row];
                    ((HF*)Cv + (long)b*sC)[(long)row*N + col] = (HF)v;
                } else if (EPI == 1) {
                    ((HF*)Cv + (long)b*sC)[(long)row*N + col] = (HF)v;
                } else {
                    float* Cf = (float*)Cv + (long)b*sC;
                    const float* Xb = Xres + (long)b*sX;
                    long o = (long)row*N + col;
                    Cf[o] = v * rowScale[row] + rowShift[row] + Xb[o];
                }
            }
        }
    }
}

// ---------------- fused scores + softmax: attn[b,n,m] ----------------
// grid (128, 8): 32 n-rows per block; 8 waves, wave w handles m in [w*128, w*128+128)
__global__ __launch_bounds__(512) void attn_softmax_kernel(
    const HF* __restrict__ Tt,   // [B][4096][256]
    const HF* __restrict__ Pt,   // [B][1024][256]
    HF* __restrict__ At)         // [B][4096][1024]
{
    int b = blockIdx.y;
    int n0 = blockIdx.x * 32;
    int tid = threadIdx.x;
    int lane = tid & 63, w = tid >> 6;
    int lr = lane & 15, lkg = lane >> 4;
    const HF* T = Tt + ((long)b*HW + n0) * CI;
    const HF* P = Pt + (long)b*Mp*CI + (long)(w*128)*CI;

    v8h af[2][8];
    #pragma unroll
    for (int rf = 0; rf < 2; ++rf)
        #pragma unroll
        for (int kf = 0; kf < 8; ++kf)
            af[rf][kf] = *(const v8h*)(T + (long)(rf*16 + lr)*CI + kf*32 + lkg*8);

    v4f acc[2][8];
    #pragma unroll
    for (int i = 0; i < 2; ++i)
        #pragma unroll
        for (int j = 0; j < 8; ++j) { v4f z = {0.f,0.f,0.f,0.f}; acc[i][j] = z; }

    #pragma unroll
    for (int kf = 0; kf < 8; ++kf) {
        #pragma unroll
        for (int nf = 0; nf < 8; ++nf) {
            v8h bfr = *(const v8h*)(P + (long)(nf*16 + lr)*CI + kf*32 + lkg*8);
            acc[0][nf] = __builtin_amdgcn_mfma_f32_16x16x32_f16(af[0][kf], bfr, acc[0][nf], 0, 0, 0);
            acc[1][nf] = __builtin_amdgcn_mfma_f32_16x16x32_f16(af[1][kf], bfr, acc[1][nf], 0, 0, 0);
        }
    }

    __shared__ float red[8][32];
    // 1) per-row max
    float rm[2][4];
    #pragma unroll
    for (int rf = 0; rf < 2; ++rf)
        #pragma unroll
        for (int r = 0; r < 4; ++r) {
            float m = -1e30f;
            #pragma unroll
            for (int nf = 0; nf < 8; ++nf) m = fmaxf(m, acc[rf][nf][r]);
            #pragma unroll
            for (int d = 1; d < 16; d <<= 1) m = fmaxf(m, __shfl_xor(m, d));
            rm[rf][r] = m;
        }
    if (lr == 0) {
        #pragma unroll
        for (int rf = 0; rf < 2; ++rf)
            #pragma unroll
            for (int r = 0; r < 4; ++r)
                red[w][rf*16 + lkg*4 + r] = rm[rf][r];
    }
    __syncthreads();
    float gm[2][4];
    #pragma unroll
    for (int rf = 0; rf < 2; ++rf)
        #pragma unroll
        for (int r = 0; r < 4; ++r) {
            float m = -1e30f;
            #pragma unroll
            for (int w2 = 0; w2 < 8; ++w2) m = fmaxf(m, red[w2][rf*16 + lkg*4 + r]);
            gm[rf][r] = m;
        }
    __syncthreads();
    // 2) exp + per-row sum
    float rs[2][4];
    #pragma unroll
    for (int rf = 0; rf < 2; ++rf)
        #pragma unroll
        for (int r = 0; r < 4; ++r) {
            float s = 0.f;
            #pragma unroll
            for (int nf = 0; nf < 8; ++nf) {
                float p = __expf(acc[rf][nf][r] - gm[rf][r]);
                acc[rf][nf][r] = p;
                s += p;
            }
            #pragma unroll
            for (int d = 1; d < 16; d <<= 1) s += __shfl_xor(s, d);
            rs[rf][r] = s;
        }
    if (lr == 0) {
        #pragma unroll
        for (int rf = 0; rf < 2; ++rf)
            #pragma unroll
            for (int r = 0; r < 4; ++r)
                red[w][rf*16 + lkg*4 + r] = rs[rf][r];
    }
    __syncthreads();
    #pragma unroll
    for (int rf = 0; rf < 2; ++rf)
        #pragma unroll
        for (int r = 0; r < 4; ++r) {
            float s = 0.f;
            #pragma unroll
            for (int w2 = 0; w2 < 8; ++w2) s += red[w2][rf*16 + lkg*4 + r];
            float inv = 1.f / s;
            int row = n0 + rf*16 + lkg*4 + r;
            #pragma unroll
            for (int nf = 0; nf < 8; ++nf) {
                int col = w*128 + nf*16 + lr;
                At[((long)b*HW + row)*Mp + col] = (HF)(acc[rf][nf][r] * inv);
            }
        }
}

extern "C" void kernel_launch(void* const* d_in, const int* in_sizes, int n_in,
                              void* d_out, int out_size, void* d_ws, size_t ws_size,
                              hipStream_t stream)
{
    const float* x     = (const float*)d_in[0];
    const float* w_g   = (const float*)d_in[1];
    const float* b_g   = (const float*)d_in[2];
    const float* w_th  = (const float*)d_in[3];
    const float* b_th  = (const float*)d_in[4];
    const float* w_ph  = (const float*)d_in[5];
    const float* b_ph  = (const float*)d_in[6];
    const float* w_out = (const float*)d_in[7];
    const float* b_out = (const float*)d_in[8];
    const float* gamma = (const float*)d_in[9];
    const float* beta  = (const float*)d_in[10];
    const float* mean  = (const float*)d_in[11];
    const float* var   = (const float*)d_in[12];
    float* out = (float*)d_out;

    char* ws = (char*)d_ws;
    size_t off = 0;
    auto alloc = [&](size_t bytes) { void* p = ws + off; off += (bytes + 255) & ~(size_t)255; return p; };
    HF*    wall  = (HF*)alloc((size_t)768*512*2);
    float* ball  = (float*)alloc(768*4);
    HF*    wo    = (HF*)alloc((size_t)512*256*2);
    float* scale = (float*)alloc(512*4);
    float* shift = (float*)alloc(512*4);
    HF*    xT    = (HF*)alloc((size_t)Bn*HW*Cc*2);
    HF*    Full  = (HF*)alloc((size_t)Bn*768*HW*2);
    HF*    Tt    = (HF*)alloc((size_t)Bn*HW*CI*2);
    HF*    Pn    = (HF*)alloc((size_t)Bn*CI*Mp*2);
    HF*    Pt    = (HF*)alloc((size_t)Bn*Mp*CI*2);
    HF*    G     = (HF*)alloc((size_t)Bn*CI*Mp*2);
    HF*    At    = (HF*)alloc((size_t)Bn*HW*Mp*2);
    HF*    Yt    = (HF*)alloc((size_t)Bn*HW*CI*2);

    prep_kernel<<<1536, 256, 0, stream>>>(w_g,b_g,w_th,b_th,w_ph,b_ph,w_out,b_out,gamma,beta,mean,var,
                                          wall, ball, wo, scale, shift);
    transpose_x_kernel<<<dim3(64,8,Bn), 256, 0, stream>>>(x, xT);
    // projections: Full[b, o, s], o: [0,256)=theta, [256,512)=phi, [512,768)=g
    gemm_bt_kernel<0><<<dim3(32,6,Bn), 256, 0, stream>>>(wall, 0, xT, (long)HW*Cc, Full, (long)768*HW,
                                                         768, HW, Cc, ball, nullptr, nullptr, nullptr, 0);
    // theta -> Tt[b, n, c]
    transpose_h_kernel<<<dim3(64,4,Bn), 256, 0, stream>>>(Full, (long)768*HW, Tt, (long)HW*CI, CI, HW);
    // phi -> pooled Pn[b, c, m] -> Pt[b, m, c]
    pool_kernel<<<8192, 256, 0, stream>>>(Full + (size_t)256*HW, (long)768*HW, Pn, (long)CI*Mp);
    transpose_h_kernel<<<dim3(16,4,Bn), 256, 0, stream>>>(Pn, (long)CI*Mp, Pt, (long)Mp*CI, CI, Mp);
    // g -> pooled G[b, c, m]
    pool_kernel<<<8192, 256, 0, stream>>>(Full + (size_t)512*HW, (long)768*HW, G, (long)CI*Mp);
    // scores + softmax -> At[b, n, m]
    attn_softmax_kernel<<<dim3(128,Bn), 512, 0, stream>>>(Tt, Pt, At);
    // Yt[b, n, c] = At @ G^T
    gemm_bt_kernel<1><<<dim3(2,32,Bn), 256, 0, stream>>>(At, (long)HW*Mp, G, (long)CI*Mp, Yt, (long)HW*CI,
                                                         HW, CI, Mp, nullptr, nullptr, nullptr, nullptr, 0);
    // out[b, co, n] = wo @ Yt^T * scale + shift + x
    gemm_bt_kernel<2><<<dim3(32,4,Bn), 256, 0, stream>>>(wo, 0, Yt, (long)HW*CI, out, (long)Cc*HW,
                                                         Cc, HW, CI, nullptr, scale, shift, x, (long)Cc*HW);
}

// Round 2
// 233.485 us; speedup vs baseline: 1.0983x; 1.0983x over previous
//
#include <hip/hip_runtime.h>

typedef _Float16 v8h __attribute__((ext_vector_type(8)));
typedef float v4f __attribute__((ext_vector_type(4)));
#define HF _Float16

// dims
#define Bn 8
#define Cc 512
#define CI 256
#define HW 4096   // 64*64
#define Mp 1024   // 32*32 pooled

// ---------------- prep: weights fp32->f16, BN fold ----------------
__global__ __launch_bounds__(256) void prep_kernel(
    const float* __restrict__ w_g, const float* __restrict__ b_g,
    const float* __restrict__ w_th, const float* __restrict__ b_th,
    const float* __restrict__ w_ph, const float* __restrict__ b_ph,
    const float* __restrict__ w_out, const float* __restrict__ b_out,
    const float* __restrict__ gamma, const float* __restrict__ beta,
    const float* __restrict__ mean, const float* __restrict__ var,
    HF* __restrict__ wall, float* __restrict__ ball,
    HF* __restrict__ wo, float* __restrict__ scale, float* __restrict__ shift)
{
    int idx = blockIdx.x * 256 + threadIdx.x;
    if (idx < 768*512) {
        int o = idx >> 9;
        float v = (o < 256) ? w_th[idx] : (o < 512) ? w_ph[idx - 256*512] : w_g[idx - 512*512];
        wall[idx] = (HF)v;
    }
    if (idx < 512*256) wo[idx] = (HF)w_out[idx];
    if (idx < 768) ball[idx] = (idx < 256) ? b_th[idx] : (idx < 512) ? b_ph[idx-256] : b_g[idx-512];
    if (idx < 512) {
        float inv = gamma[idx] * rsqrtf(var[idx] + 1e-5f);
        scale[idx] = inv;
        shift[idx] = (b_out[idx] - mean[idx]) * inv + beta[idx];
    }
}

// ---------------- transpose x: (b,c,s) fp32 -> xT (b,s,c) f16 ----------------
__global__ __launch_bounds__(256) void transpose_x_kernel(const float* __restrict__ x, HF* __restrict__ xT)
{
    __shared__ float tile[64][65];
    int b = blockIdx.z;
    int c0 = blockIdx.y * 64, s0 = blockIdx.x * 64;
    int tr = threadIdx.x >> 6, ts = threadIdx.x & 63;
    #pragma unroll
    for (int i = 0; i < 16; ++i) {
        int r = tr + i*4;
        tile[r][ts] = x[((long)(b*Cc) + c0 + r)*HW + s0 + ts];
    }
    __syncthreads();
    #pragma unroll
    for (int i = 0; i < 16; ++i) {
        int r = tr + i*4;
        xT[((long)b*HW + s0 + r)*Cc + c0 + ts] = (HF)tile[ts][r];
    }
}

// ---------------- generic f16 transpose per batch: src[R][Cn] -> dst[Cn][R] ----------------
__global__ __launch_bounds__(256) void transpose_h_kernel(const HF* __restrict__ src, long sSrc,
                                                          HF* __restrict__ dst, long sDst,
                                                          int R, int Cn)
{
    __shared__ HF tile[64][65];
    int b = blockIdx.z;
    int r0 = blockIdx.y * 64, c0 = blockIdx.x * 64;
    const HF* S = src + (long)b * sSrc;
    HF* D = dst + (long)b * sDst;
    int tr = threadIdx.x >> 6, tc = threadIdx.x & 63;
    #pragma unroll
    for (int i = 0; i < 16; ++i) {
        int r = tr + i*4;
        tile[r][tc] = S[(long)(r0 + r)*Cn + c0 + tc];
    }
    __syncthreads();
    #pragma unroll
    for (int i = 0; i < 16; ++i) {
        int r = tr + i*4;
        D[(long)(c0 + r)*R + r0 + tc] = tile[tc][r];
    }
}

// ---------------- 2x2 maxpool: src (b,c,64,64) -> dst (b,c,32,32), c-major kept ----------------
__global__ __launch_bounds__(256) void pool_kernel(const HF* __restrict__ src, long sSrc,
                                                   HF* __restrict__ dst, long sDst)
{
    long idx = (long)blockIdx.x * 256 + threadIdx.x;   // Bn*256*1024
    int m = idx & 1023;
    long bc = idx >> 10;
    int c = (int)(bc & 255);
    int b = (int)(bc >> 8);
    int h2 = m >> 5, w2 = m & 31;
    const HF* p = src + (long)b*sSrc + (long)c*HW + h2*128 + w2*2;
    float v = fmaxf(fmaxf((float)p[0], (float)p[1]), fmaxf((float)p[64], (float)p[65]));
    dst[(long)b*sDst + (long)c*Mp + m] = (HF)v;
}

// ---------------- generic tiled gemm_bt: C[i,j] = sum_k A[i,k]*B[j,k] ----------------
template<int EPI>
__global__ __launch_bounds__(256) void gemm_bt_kernel(
    const HF* __restrict__ A, long sA, const HF* __restrict__ B, long sB,
    void* __restrict__ Cv, long sC, int M, int N, int K,
    const float* __restrict__ rowBias,
    const float* __restrict__ rowScale, const float* __restrict__ rowShift,
    const float* __restrict__ Xres, long sX)
{
    __shared__ HF As[128][40];
    __shared__ HF Bs[128][40];
    int b = blockIdx.z;
    int i0 = blockIdx.y * 128;
    int j0 = blockIdx.x * 128;
    const HF* Ab = A + (long)b * sA;
    const HF* Bb = B + (long)b * sB;
    int tid = threadIdx.x;
    int lane = tid & 63, w = tid >> 6;
    int wr = w >> 1, wc = w & 1;
    int lr = lane & 15, lk = (lane >> 4) * 8;

    v4f acc[4][4];
    #pragma unroll
    for (int i = 0; i < 4; ++i)
        #pragma unroll
        for (int j = 0; j < 4; ++j) { v4f z = {0.f,0.f,0.f,0.f}; acc[i][j] = z; }

    for (int k0 = 0; k0 < K; k0 += 32) {
        #pragma unroll
        for (int q = 0; q < 2; ++q) {
            int ch = tid*2 + q;          // 0..511
            int row = ch >> 2;
            int c8 = (ch & 3) * 8;
            const uint4* ga = (const uint4*)(Ab + (long)(i0+row)*K + k0 + c8);
            *(uint4*)(&As[row][c8]) = *ga;
            const uint4* gb = (const uint4*)(Bb + (long)(j0+row)*K + k0 + c8);
            *(uint4*)(&Bs[row][c8]) = *gb;
        }
        __syncthreads();
        v8h af[4], bfr[4];
        #pragma unroll
        for (int mf = 0; mf < 4; ++mf)
            af[mf] = *(const v8h*)(&As[wr*64 + mf*16 + lr][lk]);
        #pragma unroll
        for (int nf = 0; nf < 4; ++nf)
            bfr[nf] = *(const v8h*)(&Bs[wc*64 + nf*16 + lr][lk]);
        #pragma unroll
        for (int mf = 0; mf < 4; ++mf)
            #pragma unroll
            for (int nf = 0; nf < 4; ++nf)
                acc[mf][nf] = __builtin_amdgcn_mfma_f32_16x16x32_f16(af[mf], bfr[nf], acc[mf][nf], 0, 0, 0);
        __syncthreads();
    }

    int rbase = (lane >> 4) * 4;
    #pragma unroll
    for (int mf = 0; mf < 4; ++mf) {
        #pragma unroll
        for (int nf = 0; nf < 4; ++nf) {
            #pragma unroll
            for (int r = 0; r < 4; ++r) {
                int row = i0 + wr*64 + mf*16 + rbase + r;
                int col = j0 + wc*64 + nf*16 + lr;
                float v = acc[mf][nf][r];
                if (EPI == 0) {
                    v += rowBias[row];
                    ((HF*)Cv + (long)b*sC)[(long)row*N + col] = (HF)v;
                } else if (EPI == 1) {
                    ((HF*)Cv + (long)b*sC)[(long)row*N + col] = (HF)v;
                } else {
                    float* Cf = (float*)Cv + (long)b*sC;
                    const float* Xb = Xres + (long)b*sX;
                    long o = (long)row*N + col;
                    Cf[o] = v * rowScale[row] + rowShift[row] + Xb[o];
                }
            }
        }
    }
}

// ---------------- fused flash attention: Yt[b,n,c] = softmax(T@P^T) @ G^T ----------------
// grid (32, 8): 128 n-rows/block, 8 waves x 16 rows. m-loop: 16 chunks of 64,
// P-chunk [64][256] + G-chunk [256][64] staged in padded LDS (<=2-way bank aliasing),
// register prefetch of next chunk overlapped with compute (T14 pattern).
__global__ __launch_bounds__(512) void fused_attn_kernel(
    const HF* __restrict__ Tt,   // [B][4096][256]
    const HF* __restrict__ Pt,   // [B][1024][256]
    const HF* __restrict__ G,    // [B][256][1024]
    HF* __restrict__ Yt)         // [B][4096][256]
{
    __shared__ HF P_lds[64][264];    // row stride 528B: banks spread, 2-way
    __shared__ HF G_lds[256][88];    // row stride 176B: 2-way
    __shared__ HF P_buf[8][16][88];  // per-wave P transpose buffer

    int b = blockIdx.y;
    int tid = threadIdx.x;
    int lane = tid & 63, w = tid >> 6;
    int lr = lane & 15, lkg = lane >> 4;
    int nbase = blockIdx.x * 128 + w * 16;

    const HF* Tb = Tt + ((long)b*HW + nbase) * CI;
    const HF* Pb = Pt + (long)b*Mp*CI;
    const HF* Gb = G  + (long)b*CI*Mp;

    // Q fragments held in registers for the whole kernel
    v8h af[8];
    #pragma unroll
    for (int kf = 0; kf < 8; ++kf)
        af[kf] = *(const v8h*)(Tb + (long)lr*CI + kf*32 + lkg*8);

    v4f acc_y[16];
    #pragma unroll
    for (int i = 0; i < 16; ++i) { v4f z = {0.f,0.f,0.f,0.f}; acc_y[i] = z; }
    float mrun[4] = {-1e30f,-1e30f,-1e30f,-1e30f};
    float lrun[4] = {0.f,0.f,0.f,0.f};

    uint4 pr[4], gr[4];
    // prologue: stage chunk 0
    #pragma unroll
    for (int k = 0; k < 4; ++k) {
        int id = tid + k*512;
        pr[k] = *(const uint4*)(Pb + (long)(id>>5)*CI + (id&31)*8);
        gr[k] = *(const uint4*)(Gb + (long)(id>>3)*Mp + (id&7)*8);
    }
    #pragma unroll
    for (int k = 0; k < 4; ++k) {
        int id = tid + k*512;
        *(uint4*)(&P_lds[id>>5][(id&31)*8]) = pr[k];
        *(uint4*)(&G_lds[id>>3][(id&7)*8]) = gr[k];
    }
    __syncthreads();

    for (int t = 0; t < 16; ++t) {
        // issue next chunk's global loads early (latency hides under compute)
        if (t < 15) {
            int m0 = (t+1) * 64;
            #pragma unroll
            for (int k = 0; k < 4; ++k) {
                int id = tid + k*512;
                pr[k] = *(const uint4*)(Pb + (long)(m0 + (id>>5))*CI + (id&31)*8);
                gr[k] = *(const uint4*)(Gb + (long)(id>>3)*Mp + m0 + (id&7)*8);
            }
        }
        // QK^T: S[16 n][64 m]
        v4f acc[4];
        #pragma unroll
        for (int nf = 0; nf < 4; ++nf) { v4f z = {0.f,0.f,0.f,0.f}; acc[nf] = z; }
        #pragma unroll
        for (int kf = 0; kf < 8; ++kf) {
            #pragma unroll
            for (int nf = 0; nf < 4; ++nf) {
                v8h bfr = *(const v8h*)(&P_lds[nf*16 + lr][kf*32 + lkg*8]);
                acc[nf] = __builtin_amdgcn_mfma_f32_16x16x32_f16(af[kf], bfr, acc[nf], 0, 0, 0);
            }
        }
        // online softmax (rows: lkg*4+r, cols: nf*16+lr)
        #pragma unroll
        for (int r = 0; r < 4; ++r) {
            float cm = fmaxf(fmaxf(acc[0][r], acc[1][r]), fmaxf(acc[2][r], acc[3][r]));
            #pragma unroll
            for (int d = 1; d < 16; d <<= 1) cm = fmaxf(cm, __shfl_xor(cm, d));
            float mnew = fmaxf(mrun[r], cm);
            float alpha = __expf(mrun[r] - mnew);
            mrun[r] = mnew;
            lrun[r] *= alpha;
            #pragma unroll
            for (int cf = 0; cf < 16; ++cf) acc_y[cf][r] *= alpha;
            float rs = 0.f;
            #pragma unroll
            for (int nf = 0; nf < 4; ++nf) {
                float p = __expf(acc[nf][r] - mnew);
                rs += p;
                P_buf[w][lkg*4 + r][nf*16 + lr] = (HF)p;
            }
            #pragma unroll
            for (int d = 1; d < 16; d <<= 1) rs += __shfl_xor(rs, d);
            lrun[r] += rs;
        }
        // PV: Y[16 n][256 c] += P(16x64) @ G_chunk^T
        v8h ap0 = *(const v8h*)(&P_buf[w][lr][lkg*8]);
        v8h ap1 = *(const v8h*)(&P_buf[w][lr][32 + lkg*8]);
        #pragma unroll
        for (int cf = 0; cf < 16; ++cf) {
            v8h bg0 = *(const v8h*)(&G_lds[cf*16 + lr][lkg*8]);
            acc_y[cf] = __builtin_amdgcn_mfma_f32_16x16x32_f16(ap0, bg0, acc_y[cf], 0, 0, 0);
            v8h bg1 = *(const v8h*)(&G_lds[cf*16 + lr][32 + lkg*8]);
            acc_y[cf] = __builtin_amdgcn_mfma_f32_16x16x32_f16(ap1, bg1, acc_y[cf], 0, 0, 0);
        }
        __syncthreads();
        // write next chunk into LDS after all waves finished reading
        if (t < 15) {
            #pragma unroll
            for (int k = 0; k < 4; ++k) {
                int id = tid + k*512;
                *(uint4*)(&P_lds[id>>5][(id&31)*8]) = pr[k];
                *(uint4*)(&G_lds[id>>3][(id&7)*8]) = gr[k];
            }
        }
        __syncthreads();
    }

    // epilogue: Y /= l, write f16
    HF* Yb = Yt + ((long)b*HW + nbase) * CI;
    #pragma unroll
    for (int r = 0; r < 4; ++r) {
        float inv = 1.f / lrun[r];
        #pragma unroll
        for (int cf = 0; cf < 16; ++cf)
            Yb[(long)(lkg*4 + r)*CI + cf*16 + lr] = (HF)(acc_y[cf][r] * inv);
    }
}

extern "C" void kernel_launch(void* const* d_in, const int* in_sizes, int n_in,
                              void* d_out, int out_size, void* d_ws, size_t ws_size,
                              hipStream_t stream)
{
    const float* x     = (const float*)d_in[0];
    const float* w_g   = (const float*)d_in[1];
    const float* b_g   = (const float*)d_in[2];
    const float* w_th  = (const float*)d_in[3];
    const float* b_th  = (const float*)d_in[4];
    const float* w_ph  = (const float*)d_in[5];
    const float* b_ph  = (const float*)d_in[6];
    const float* w_out = (const float*)d_in[7];
    const float* b_out = (const float*)d_in[8];
    const float* gamma = (const float*)d_in[9];
    const float* beta  = (const float*)d_in[10];
    const float* mean  = (const float*)d_in[11];
    const float* var   = (const float*)d_in[12];
    float* out = (float*)d_out;

    char* ws = (char*)d_ws;
    size_t off = 0;
    auto alloc = [&](size_t bytes) { void* p = ws + off; off += (bytes + 255) & ~(size_t)255; return p; };
    HF*    wall  = (HF*)alloc((size_t)768*512*2);
    float* ball  = (float*)alloc(768*4);
    HF*    wo    = (HF*)alloc((size_t)512*256*2);
    float* scale = (float*)alloc(512*4);
    float* shift = (float*)alloc(512*4);
    HF*    xT    = (HF*)alloc((size_t)Bn*HW*Cc*2);
    HF*    Full  = (HF*)alloc((size_t)Bn*768*HW*2);
    HF*    Tt    = (HF*)alloc((size_t)Bn*HW*CI*2);
    HF*    Pn    = (HF*)alloc((size_t)Bn*CI*Mp*2);
    HF*    Pt    = (HF*)alloc((size_t)Bn*Mp*CI*2);
    HF*    G     = (HF*)alloc((size_t)Bn*CI*Mp*2);
    HF*    Yt    = (HF*)alloc((size_t)Bn*HW*CI*2);

    prep_kernel<<<1536, 256, 0, stream>>>(w_g,b_g,w_th,b_th,w_ph,b_ph,w_out,b_out,gamma,beta,mean,var,
                                          wall, ball, wo, scale, shift);
    transpose_x_kernel<<<dim3(64,8,Bn), 256, 0, stream>>>(x, xT);
    // projections: Full[b, o, s], o: [0,256)=theta, [256,512)=phi, [512,768)=g
    gemm_bt_kernel<0><<<dim3(32,6,Bn), 256, 0, stream>>>(wall, 0, xT, (long)HW*Cc, Full, (long)768*HW,
                                                         768, HW, Cc, ball, nullptr, nullptr, nullptr, 0);
    // theta -> Tt[b, n, c]
    transpose_h_kernel<<<dim3(64,4,Bn), 256, 0, stream>>>(Full, (long)768*HW, Tt, (long)HW*CI, CI, HW);
    // phi -> pooled Pn[b, c, m] -> Pt[b, m, c]
    pool_kernel<<<8192, 256, 0, stream>>>(Full + (size_t)256*HW, (long)768*HW, Pn, (long)CI*Mp);
    transpose_h_kernel<<<dim3(16,4,Bn), 256, 0, stream>>>(Pn, (long)CI*Mp, Pt, (long)Mp*CI, CI, Mp);
    // g -> pooled G[b, c, m]
    pool_kernel<<<8192, 256, 0, stream>>>(Full + (size_t)512*HW, (long)768*HW, G, (long)CI*Mp);
    // fused scores+softmax+PV -> Yt[b, n, c]
    fused_attn_kernel<<<dim3(32,Bn), 512, 0, stream>>>(Tt, Pt, G, Yt);
    // out[b, co, n] = wo @ Yt^T * scale + shift + x
    gemm_bt_kernel<2><<<dim3(32,4,Bn), 256, 0, stream>>>(wo, 0, Yt, (long)HW*CI, out, (long)Cc*HW,
                                                         Cc, HW, CI, nullptr, scale, shift, x, (long)Cc*HW);
}

// Round 3
// 219.563 us; speedup vs baseline: 1.1679x; 1.0634x over previous
//
#include <hip/hip_runtime.h>

typedef _Float16 v8h __attribute__((ext_vector_type(8)));
typedef float v4f __attribute__((ext_vector_type(4)));
#define HF _Float16

// dims
#define Bn 8
#define Cc 512
#define CI 256
#define HW 4096   // 64*64
#define Mp 1024   // 32*32 pooled

__device__ __forceinline__ void gload16(const HF* g, HF* l) {
    __builtin_amdgcn_global_load_lds((const __attribute__((address_space(1))) void*)g,
                                     (__attribute__((address_space(3))) void*)l, 16, 0, 0);
}

// ---------------- prep: weights fp32->f16, BN fold ----------------
__global__ __launch_bounds__(256) void prep_kernel(
    const float* __restrict__ w_g, const float* __restrict__ b_g,
    const float* __restrict__ w_th, const float* __restrict__ b_th,
    const float* __restrict__ w_ph, const float* __restrict__ b_ph,
    const float* __restrict__ w_out, const float* __restrict__ b_out,
    const float* __restrict__ gamma, const float* __restrict__ beta,
    const float* __restrict__ mean, const float* __restrict__ var,
    HF* __restrict__ wall, float* __restrict__ ball,
    HF* __restrict__ wo, float* __restrict__ scale, float* __restrict__ shift)
{
    int idx = blockIdx.x * 256 + threadIdx.x;
    if (idx < 768*512) {
        int o = idx >> 9;
        float v = (o < 256) ? w_th[idx] : (o < 512) ? w_ph[idx - 256*512] : w_g[idx - 512*512];
        wall[idx] = (HF)v;
    }
    if (idx < 512*256) wo[idx] = (HF)w_out[idx];
    if (idx < 768) ball[idx] = (idx < 256) ? b_th[idx] : (idx < 512) ? b_ph[idx-256] : b_g[idx-512];
    if (idx < 512) {
        float inv = gamma[idx] * rsqrtf(var[idx] + 1e-5f);
        scale[idx] = inv;
        shift[idx] = (b_out[idx] - mean[idx]) * inv + beta[idx];
    }
}

// ---------------- transpose x: (b,c,s) fp32 -> xT (b,s,c) f16 ----------------
__global__ __launch_bounds__(256) void transpose_x_kernel(const float* __restrict__ x, HF* __restrict__ xT)
{
    __shared__ float tile[64][65];
    int b = blockIdx.z;
    int c0 = blockIdx.y * 64, s0 = blockIdx.x * 64;
    int tr = threadIdx.x >> 6, ts = threadIdx.x & 63;
    #pragma unroll
    for (int i = 0; i < 16; ++i) {
        int r = tr + i*4;
        tile[r][ts] = x[((long)(b*Cc) + c0 + r)*HW + s0 + ts];
    }
    __syncthreads();
    #pragma unroll
    for (int i = 0; i < 16; ++i) {
        int r = tr + i*4;
        xT[((long)b*HW + s0 + r)*Cc + c0 + ts] = (HF)tile[ts][r];
    }
}

// ---------------- generic f16 transpose per batch: src[R][Cn] -> dst[Cn][R] ----------------
__global__ __launch_bounds__(256) void transpose_h_kernel(const HF* __restrict__ src, long sSrc,
                                                          HF* __restrict__ dst, long sDst,
                                                          int R, int Cn)
{
    __shared__ HF tile[64][65];
    int b = blockIdx.z;
    int r0 = blockIdx.y * 64, c0 = blockIdx.x * 64;
    const HF* S = src + (long)b * sSrc;
    HF* D = dst + (long)b * sDst;
    int tr = threadIdx.x >> 6, tc = threadIdx.x & 63;
    #pragma unroll
    for (int i = 0; i < 16; ++i) {
        int r = tr + i*4;
        tile[r][tc] = S[(long)(r0 + r)*Cn + c0 + tc];
    }
    __syncthreads();
    #pragma unroll
    for (int i = 0; i < 16; ++i) {
        int r = tr + i*4;
        D[(long)(c0 + r)*R + r0 + tc] = tile[tc][r];
    }
}

// ---------------- 2x2 maxpool: src (b,c,64,64) -> dst (b,c,32,32), c-major kept ----------------
__global__ __launch_bounds__(256) void pool_kernel(const HF* __restrict__ src, long sSrc,
                                                   HF* __restrict__ dst, long sDst)
{
    long idx = (long)blockIdx.x * 256 + threadIdx.x;   // Bn*256*1024
    int m = idx & 1023;
    long bc = idx >> 10;
    int c = (int)(bc & 255);
    int b = (int)(bc >> 8);
    int h2 = m >> 5, w2 = m & 31;
    const HF* p = src + (long)b*sSrc + (long)c*HW + h2*128 + w2*2;
    float v = fmaxf(fmaxf((float)p[0], (float)p[1]), fmaxf((float)p[64], (float)p[65]));
    dst[(long)b*sDst + (long)c*Mp + m] = (HF)v;
}

// ---------------- generic tiled gemm_bt: C[i,j] = sum_k A[i,k]*B[j,k] ----------------
template<int EPI>
__global__ __launch_bounds__(256) void gemm_bt_kernel(
    const HF* __restrict__ A, long sA, const HF* __restrict__ B, long sB,
    void* __restrict__ Cv, long sC, int M, int N, int K,
    const float* __restrict__ rowBias,
    const float* __restrict__ rowScale, const float* __restrict__ rowShift,
    const float* __restrict__ Xres, long sX)
{
    __shared__ HF As[128][40];
    __shared__ HF Bs[128][40];
    int b = blockIdx.z;
    int i0 = blockIdx.y * 128;
    int j0 = blockIdx.x * 128;
    const HF* Ab = A + (long)b * sA;
    const HF* Bb = B + (long)b * sB;
    int tid = threadIdx.x;
    int lane = tid & 63, w = tid >> 6;
    int wr = w >> 1, wc = w & 1;
    int lr = lane & 15, lk = (lane >> 4) * 8;

    v4f acc[4][4];
    #pragma unroll
    for (int i = 0; i < 4; ++i)
        #pragma unroll
        for (int j = 0; j < 4; ++j) { v4f z = {0.f,0.f,0.f,0.f}; acc[i][j] = z; }

    for (int k0 = 0; k0 < K; k0 += 32) {
        #pragma unroll
        for (int q = 0; q < 2; ++q) {
            int ch = tid*2 + q;          // 0..511
            int row = ch >> 2;
            int c8 = (ch & 3) * 8;
            const uint4* ga = (const uint4*)(Ab + (long)(i0+row)*K + k0 + c8);
            *(uint4*)(&As[row][c8]) = *ga;
            const uint4* gb = (const uint4*)(Bb + (long)(j0+row)*K + k0 + c8);
            *(uint4*)(&Bs[row][c8]) = *gb;
        }
        __syncthreads();
        v8h af[4], bfr[4];
        #pragma unroll
        for (int mf = 0; mf < 4; ++mf)
            af[mf] = *(const v8h*)(&As[wr*64 + mf*16 + lr][lk]);
        #pragma unroll
        for (int nf = 0; nf < 4; ++nf)
            bfr[nf] = *(const v8h*)(&Bs[wc*64 + nf*16 + lr][lk]);
        #pragma unroll
        for (int mf = 0; mf < 4; ++mf)
            #pragma unroll
            for (int nf = 0; nf < 4; ++nf)
                acc[mf][nf] = __builtin_amdgcn_mfma_f32_16x16x32_f16(af[mf], bfr[nf], acc[mf][nf], 0, 0, 0);
        __syncthreads();
    }

    int rbase = (lane >> 4) * 4;
    #pragma unroll
    for (int mf = 0; mf < 4; ++mf) {
        #pragma unroll
        for (int nf = 0; nf < 4; ++nf) {
            #pragma unroll
            for (int r = 0; r < 4; ++r) {
                int row = i0 + wr*64 + mf*16 + rbase + r;
                int col = j0 + wc*64 + nf*16 + lr;
                float v = acc[mf][nf][r];
                if (EPI == 0) {
                    v += rowBias[row];
                    ((HF*)Cv + (long)b*sC)[(long)row*N + col] = (HF)v;
                } else if (EPI == 1) {
                    ((HF*)Cv + (long)b*sC)[(long)row*N + col] = (HF)v;
                } else {
                    float* Cf = (float*)Cv + (long)b*sC;
                    const float* Xb = Xres + (long)b*sX;
                    long o = (long)row*N + col;
                    Cf[o] = v * rowScale[row] + rowShift[row] + Xb[o];
                }
            }
        }
    }
}

// ---------------- fused flash attention v2 ----------------
// 512 blocks (64 x 8 batches), 256 thr = 4 waves x 16 rows. m-chunks of 32,
// double-buffered LDS staged via global_load_lds with pre-swizzled global src
// (linear LDS dest + XOR-swz read). One barrier per chunk. 68 KB LDS -> 2 blocks/CU.
__global__ __launch_bounds__(256) void fused_attn_kernel(
    const HF* __restrict__ Tt,   // [B][4096][256]
    const HF* __restrict__ Pt,   // [B][1024][256]
    const HF* __restrict__ G,    // [B][256][1024]
    HF* __restrict__ Yt)         // [B][4096][256]
{
    __shared__ HF P_lds[2][32][256];   // 32 KB: m-rows x c, swz ((row&7)<<3)
    __shared__ HF G_lds[2][256][32];   // 32 KB: c-rows x m, swz ((row&3)<<3)
    __shared__ HF P_buf[4][16][32];    // 4 KB per-wave P^T, swz ((row&3)<<3)

    int b = blockIdx.y;
    int tid = threadIdx.x;
    int lane = tid & 63, w = tid >> 6;
    int lr = lane & 15, lkg = lane >> 4;
    int nbase = blockIdx.x * 64 + w * 16;

    const HF* Tb = Tt + ((long)b*HW + nbase) * CI;
    const HF* Pb = Pt + (long)b*Mp*CI;
    const HF* Gb = G  + (long)b*CI*Mp;

    // stage chunk m0 into buffer bsel: wave w issues its 4 P + 4 G gload_lds
    auto stage = [&](int bsel, int m0) {
        #pragma unroll
        for (int q = 0; q < 4; ++q) {
            int i = w*4 + q;
            // P: dest halves [i*512, i*512+512) = 2 rows of [32][256]
            int dp = i*512 + lane*8;
            int prow = dp >> 8;
            int pcol = (dp & 255) ^ ((prow & 7) << 3);
            gload16(Pb + (long)(m0 + prow)*CI + pcol, &P_lds[bsel][0][0] + i*512);
            // G: dest halves = 16 rows of [256][32]
            int dg = i*512 + lane*8;
            int grow = dg >> 5;
            int gcol = (dg & 31) ^ ((grow & 3) << 3);
            gload16(Gb + (long)grow*Mp + m0 + gcol, &G_lds[bsel][0][0] + i*512);
        }
    };

    // Q fragments in registers for whole kernel
    v8h af[8];
    #pragma unroll
    for (int kf = 0; kf < 8; ++kf)
        af[kf] = *(const v8h*)(Tb + (long)lr*CI + kf*32 + lkg*8);

    v4f acc_y[16];
    #pragma unroll
    for (int i = 0; i < 16; ++i) { v4f z = {0.f,0.f,0.f,0.f}; acc_y[i] = z; }
    float mrun[4] = {-1e30f,-1e30f,-1e30f,-1e30f};
    float lrun[4] = {0.f,0.f,0.f,0.f};

    stage(0, 0);
    __syncthreads();

    int cur = 0;
    for (int t = 0; t < 32; ++t) {
        if (t < 31) stage(cur ^ 1, (t+1)*32);

        // QK^T: S[16 n][32 m] from P_lds[cur]
        v4f acc[2];
        #pragma unroll
        for (int nf = 0; nf < 2; ++nf) { v4f z = {0.f,0.f,0.f,0.f}; acc[nf] = z; }
        __builtin_amdgcn_s_setprio(1);
        #pragma unroll
        for (int kf = 0; kf < 8; ++kf) {
            #pragma unroll
            for (int nf = 0; nf < 2; ++nf) {
                int prow = nf*16 + lr;
                v8h bfr = *(const v8h*)(&P_lds[cur][prow][(kf*32 + lkg*8) ^ ((prow & 7) << 3)]);
                acc[nf] = __builtin_amdgcn_mfma_f32_16x16x32_f16(af[kf], bfr, acc[nf], 0, 0, 0);
            }
        }
        __builtin_amdgcn_s_setprio(0);

        // online softmax (row = lkg*4 + r, cols nf*16+lr)
        #pragma unroll
        for (int r = 0; r < 4; ++r) {
            float cm = fmaxf(acc[0][r], acc[1][r]);
            #pragma unroll
            for (int d = 1; d < 16; d <<= 1) cm = fmaxf(cm, __shfl_xor(cm, d));
            float mold = mrun[r];
            float mnew = fmaxf(mold, cm);
            mrun[r] = mnew;
            if (!__all(cm <= mold)) {           // T13: skip rescale when no growth
                float alpha = __expf(mold - mnew);
                lrun[r] *= alpha;
                #pragma unroll
                for (int cf = 0; cf < 16; ++cf) acc_y[cf][r] *= alpha;
            }
            int row = lkg*4 + r;
            float rs = 0.f;
            #pragma unroll
            for (int nf = 0; nf < 2; ++nf) {
                float p = __expf(acc[nf][r] - mnew);
                rs += p;
                P_buf[w][row][(nf*16 + lr) ^ ((row & 3) << 3)] = (HF)p;
            }
            #pragma unroll
            for (int d = 1; d < 16; d <<= 1) rs += __shfl_xor(rs, d);
            lrun[r] += rs;
        }

        // PV: Y[16 n][256 c] += P(16x32) @ G_chunk^T
        v8h ap = *(const v8h*)(&P_buf[w][lr][(lkg*8) ^ ((lr & 3) << 3)]);
        __builtin_amdgcn_s_setprio(1);
        #pragma unroll
        for (int cf = 0; cf < 16; ++cf) {
            int grow = cf*16 + lr;
            v8h bg = *(const v8h*)(&G_lds[cur][grow][(lkg*8) ^ ((grow & 3) << 3)]);
            acc_y[cf] = __builtin_amdgcn_mfma_f32_16x16x32_f16(ap, bg, acc_y[cf], 0, 0, 0);
        }
        __builtin_amdgcn_s_setprio(0);

        __syncthreads();   // readers done with cur; gloads to cur^1 drained (implicit vmcnt)
        cur ^= 1;
    }

    // epilogue: Y /= l, write f16
    HF* Yb = Yt + ((long)b*HW + nbase) * CI;
    #pragma unroll
    for (int r = 0; r < 4; ++r) {
        float inv = 1.f / lrun[r];
        #pragma unroll
        for (int cf = 0; cf < 16; ++cf)
            Yb[(long)(lkg*4 + r)*CI + cf*16 + lr] = (HF)(acc_y[cf][r] * inv);
    }
}

extern "C" void kernel_launch(void* const* d_in, const int* in_sizes, int n_in,
                              void* d_out, int out_size, void* d_ws, size_t ws_size,
                              hipStream_t stream)
{
    const float* x     = (const float*)d_in[0];
    const float* w_g   = (const float*)d_in[1];
    const float* b_g   = (const float*)d_in[2];
    const float* w_th  = (const float*)d_in[3];
    const float* b_th  = (const float*)d_in[4];
    const float* w_ph  = (const float*)d_in[5];
    const float* b_ph  = (const float*)d_in[6];
    const float* w_out = (const float*)d_in[7];
    const float* b_out = (const float*)d_in[8];
    const float* gamma = (const float*)d_in[9];
    const float* beta  = (const float*)d_in[10];
    const float* mean  = (const float*)d_in[11];
    const float* var   = (const float*)d_in[12];
    float* out = (float*)d_out;

    char* ws = (char*)d_ws;
    size_t off = 0;
    auto alloc = [&](size_t bytes) { void* p = ws + off; off += (bytes + 255) & ~(size_t)255; return p; };
    HF*    wall  = (HF*)alloc((size_t)768*512*2);
    float* ball  = (float*)alloc(768*4);
    HF*    wo    = (HF*)alloc((size_t)512*256*2);
    float* scale = (float*)alloc(512*4);
    float* shift = (float*)alloc(512*4);
    HF*    xT    = (HF*)alloc((size_t)Bn*HW*Cc*2);
    HF*    Full  = (HF*)alloc((size_t)Bn*768*HW*2);
    HF*    Tt    = (HF*)alloc((size_t)Bn*HW*CI*2);
    HF*    Pn    = (HF*)alloc((size_t)Bn*CI*Mp*2);
    HF*    Pt    = (HF*)alloc((size_t)Bn*Mp*CI*2);
    HF*    G     = (HF*)alloc((size_t)Bn*CI*Mp*2);
    HF*    Yt    = (HF*)alloc((size_t)Bn*HW*CI*2);

    prep_kernel<<<1536, 256, 0, stream>>>(w_g,b_g,w_th,b_th,w_ph,b_ph,w_out,b_out,gamma,beta,mean,var,
                                          wall, ball, wo, scale, shift);
    transpose_x_kernel<<<dim3(64,8,Bn), 256, 0, stream>>>(x, xT);
    // projections: Full[b, o, s], o: [0,256)=theta, [256,512)=phi, [512,768)=g
    gemm_bt_kernel<0><<<dim3(32,6,Bn), 256, 0, stream>>>(wall, 0, xT, (long)HW*Cc, Full, (long)768*HW,
                                                         768, HW, Cc, ball, nullptr, nullptr, nullptr, 0);
    // theta -> Tt[b, n, c]
    transpose_h_kernel<<<dim3(64,4,Bn), 256, 0, stream>>>(Full, (long)768*HW, Tt, (long)HW*CI, CI, HW);
    // phi -> pooled Pn[b, c, m] -> Pt[b, m, c]
    pool_kernel<<<8192, 256, 0, stream>>>(Full + (size_t)256*HW, (long)768*HW, Pn, (long)CI*Mp);
    transpose_h_kernel<<<dim3(16,4,Bn), 256, 0, stream>>>(Pn, (long)CI*Mp, Pt, (long)Mp*CI, CI, Mp);
    // g -> pooled G[b, c, m]
    pool_kernel<<<8192, 256, 0, stream>>>(Full + (size_t)512*HW, (long)768*HW, G, (long)CI*Mp);
    // fused scores+softmax+PV -> Yt[b, n, c]
    fused_attn_kernel<<<dim3(64,Bn), 256, 0, stream>>>(Tt, Pt, G, Yt);
    // out[b, co, n] = wo @ Yt^T * scale + shift + x
    gemm_bt_kernel<2><<<dim3(32,4,Bn), 256, 0, stream>>>(wo, 0, Yt, (long)HW*CI, out, (long)Cc*HW,
                                                         Cc, HW, CI, nullptr, scale, shift, x, (long)Cc*HW);
}